// Round 1
// baseline (448.812 us; speedup 1.0000x reference)
//
#include <hip/hip_runtime.h>
#include <hip/hip_bf16.h>

#define B_    64
#define S_    4096
#define DIM_  256
#define DA_   64
#define NEG_  (-1e30f)

typedef __attribute__((ext_vector_type(8))) short short8;
typedef __attribute__((ext_vector_type(4))) float float4v;

static __device__ inline unsigned short f2bf(float x) {
    union { float f; unsigned u; } v; v.f = x;
    unsigned r = v.u + 0x7fffu + ((v.u >> 16) & 1u);  // round-nearest-even
    return (unsigned short)(r >> 16);
}

// Kernel 0: convert A (DIM x DA fp32) -> at (DA x DIM bf16, transposed),
// and detect mask encoding (block 0): flag=1 => int32 elements, flag=0 => 1-byte.
__global__ __launch_bounds__(256) void prep_kernel(
    const float* __restrict__ a, const void* __restrict__ mask,
    unsigned short* __restrict__ at, int* __restrict__ flag)
{
    int idx = blockIdx.x * 256 + threadIdx.x;   // 0..16383
    int k = idx >> 8;      // 0..63  (DA)
    int d = idx & 255;     // 0..255 (DIM)
    at[k * DIM_ + d] = f2bf(a[d * DA_ + k]);

    if (blockIdx.x == 0) {
        __shared__ int anynz;
        if (threadIdx.x == 0) anynz = 0;
        __syncthreads();
        const unsigned char* mb = (const unsigned char*)mask;
        int base = threadIdx.x * 4;   // scan first 1024 bytes
        int v = mb[base + 1] | mb[base + 2] | mb[base + 3];
        if (v) atomicOr(&anynz, 1);
        __syncthreads();
        if (threadIdx.x == 0) *flag = (anynz == 0) ? 1 : 0;
    }
}

// Kernel 1: e[b,s] = sum_k tanh( dot(h[b,s,:], A[:,k]) ) * bvec[k]
// One block = 64 sequence rows. MFMA 16x16x32 bf16, N=64 (4 n-tiles), K=256.
__global__ __launch_bounds__(256) void logits_kernel(
    const float* __restrict__ h, const unsigned short* __restrict__ at,
    const float* __restrict__ bvec, float* __restrict__ e)
{
    __shared__ unsigned short hs[64 * 264];   // 64 rows, K=256 + 8 pad (bf16)
    const int t = threadIdx.x;
    const long long s0 = (long long)blockIdx.x * 64;
    const float* hblk = h + s0 * DIM_;

    // Stage: 64x256 fp32 -> bf16 LDS (4096 float4s, 16 per thread)
    #pragma unroll
    for (int j = 0; j < 16; ++j) {
        int f = t + j * 256;          // float4 index
        int row = f >> 6;
        int col = (f & 63) * 4;
        float4 v = *(const float4*)(hblk + row * DIM_ + col);
        unsigned b0 = f2bf(v.x), b1 = f2bf(v.y), b2 = f2bf(v.z), b3 = f2bf(v.w);
        uint2 packed;
        packed.x = b0 | (b1 << 16);
        packed.y = b2 | (b3 << 16);
        *(uint2*)&hs[row * 264 + col] = packed;
    }
    __syncthreads();

    const int wave = t >> 6;
    const int lane = t & 63;
    const int quad = lane >> 4;     // 0..3
    const int nrow = lane & 15;     // m-index for A frag, n-index for B frag, col for D

    float4v acc[4];
    #pragma unroll
    for (int nt = 0; nt < 4; ++nt) acc[nt] = (float4v){0.f, 0.f, 0.f, 0.f};

    const unsigned short* hrow = &hs[(wave * 16 + nrow) * 264];
    #pragma unroll
    for (int kb = 0; kb < 8; ++kb) {
        short8 afrag = *(const short8*)(hrow + kb * 32 + quad * 8);
        #pragma unroll
        for (int nt = 0; nt < 4; ++nt) {
            short8 bfrag = *(const short8*)(at + (nt * 16 + nrow) * DIM_ + kb * 32 + quad * 8);
            acc[nt] = __builtin_amdgcn_mfma_f32_16x16x32_bf16(afrag, bfrag, acc[nt], 0, 0, 0);
        }
    }

    // Epilogue: e[row] = sum over 64 cols of tanh(z)*b[col].
    // D layout: col = nrow (per n-tile), row = quad*4 + reg.
    float bv[4];
    #pragma unroll
    for (int nt = 0; nt < 4; ++nt) bv[nt] = bvec[nt * 16 + nrow];

    #pragma unroll
    for (int r = 0; r < 4; ++r) {
        float p = 0.f;
        #pragma unroll
        for (int nt = 0; nt < 4; ++nt) p += tanhf(acc[nt][r]) * bv[nt];
        // reduce across the 16 lanes of this quad (cols)
        p += __shfl_xor(p, 1);
        p += __shfl_xor(p, 2);
        p += __shfl_xor(p, 4);
        p += __shfl_xor(p, 8);
        if (nrow == r)
            e[s0 + wave * 16 + quad * 4 + r] = p;
    }
}

// Kernel 2: per-batch masked softmax over S, in place (e -> weights).
__global__ __launch_bounds__(1024) void softmax_kernel(
    float* __restrict__ e, const void* __restrict__ mask, const int* __restrict__ flag)
{
    const int b = blockIdx.x;
    const int t = threadIdx.x;
    const bool int32enc = (*flag != 0);
    const long long base = (long long)b * S_;

    float ev[4];
    #pragma unroll
    for (int i = 0; i < 4; ++i) {
        int s = t + i * 1024;
        float x = e[base + s];
        int m;
        if (int32enc) m = ((const int*)mask)[base + s];
        else          m = ((const unsigned char*)mask)[base + s];
        ev[i] = m ? NEG_ : x;
    }

    __shared__ float red[16];
    float mx = fmaxf(fmaxf(ev[0], ev[1]), fmaxf(ev[2], ev[3]));
    #pragma unroll
    for (int off = 32; off >= 1; off >>= 1) mx = fmaxf(mx, __shfl_xor(mx, off));
    if ((t & 63) == 0) red[t >> 6] = mx;
    __syncthreads();
    float m = red[0];
    #pragma unroll
    for (int i = 1; i < 16; ++i) m = fmaxf(m, red[i]);
    __syncthreads();

    float ex[4];
    float l = 0.f;
    #pragma unroll
    for (int i = 0; i < 4; ++i) { ex[i] = __expf(ev[i] - m); l += ex[i]; }
    #pragma unroll
    for (int off = 32; off >= 1; off >>= 1) l += __shfl_xor(l, off);
    if ((t & 63) == 0) red[t >> 6] = l;
    __syncthreads();
    float lt = 0.f;
    #pragma unroll
    for (int i = 0; i < 16; ++i) lt += red[i];

    float inv = 1.0f / lt;
    #pragma unroll
    for (int i = 0; i < 4; ++i) e[base + t + i * 1024] = ex[i] * inv;
}

// Kernel 3: out[b,d] = sum_s w[b,s] * h[b,s,d]. Grid = B * 16 chunks of 256 s.
__global__ __launch_bounds__(256) void wsum_kernel(
    const float* __restrict__ h, const float* __restrict__ w, float* __restrict__ out)
{
    const int b = blockIdx.x >> 4;
    const int c = blockIdx.x & 15;
    const int t = threadIdx.x;
    __shared__ float wch[256];
    const long long s0 = (long long)b * S_ + c * 256;
    wch[t] = w[s0 + t];
    __syncthreads();

    const float* hb = h + s0 * DIM_;
    float acc = 0.f;
    #pragma unroll 8
    for (int i = 0; i < 256; ++i)
        acc = fmaf(wch[i], hb[(size_t)i * DIM_ + t], acc);
    atomicAdd(&out[b * DIM_ + t], acc);
}

extern "C" void kernel_launch(void* const* d_in, const int* in_sizes, int n_in,
                              void* d_out, int out_size, void* d_ws, size_t ws_size,
                              hipStream_t stream) {
    const float* h    = (const float*)d_in[0];
    const void*  mask = d_in[1];
    const float* a    = (const float*)d_in[2];
    const float* bvec = (const float*)d_in[3];
    float* out = (float*)d_out;

    char* ws = (char*)d_ws;
    unsigned short* at = (unsigned short*)ws;        // 32768 B (DA x DIM bf16)
    int* flag          = (int*)(ws + 32768);
    float* e           = (float*)(ws + 36864);       // B*S fp32 = 1 MiB

    hipMemsetAsync(d_out, 0, (size_t)B_ * DIM_ * sizeof(float), stream);
    prep_kernel<<<64, 256, 0, stream>>>(a, mask, at, flag);
    logits_kernel<<<(B_ * S_) / 64, 256, 0, stream>>>(h, at, bvec, e);
    softmax_kernel<<<B_, 1024, 0, stream>>>(e, mask, flag);
    wsum_kernel<<<B_ * 16, 256, 0, stream>>>(h, e, out);
}

// Round 2
// 420.867 us; speedup vs baseline: 1.0664x; 1.0664x over previous
//
#include <hip/hip_runtime.h>
#include <hip/hip_bf16.h>

#define B_    64
#define S_    4096
#define DIM_  256
#define DA_   64
#define NEG_  (-1e30f)

typedef __attribute__((ext_vector_type(8))) short short8;
typedef __attribute__((ext_vector_type(4))) float float4v;

static __device__ inline unsigned short f2bf(float x) {
    union { float f; unsigned u; } v; v.f = x;
    unsigned r = v.u + 0x7fffu + ((v.u >> 16) & 1u);  // round-nearest-even
    return (unsigned short)(r >> 16);
}

// Kernel 0: build at_sw = A swizzled into exact MFMA B-fragment order (bf16),
// and detect mask encoding: flag=1 => int32 elements, flag=0 => 1-byte.
// at_sw half index: ((nt*8+kb)*64 + lane)*8 + j
//   value = A[d][kf], d = kb*32 + (lane>>4)*8 + j, kf = nt*16 + (lane&15)
__global__ __launch_bounds__(256) void prep_kernel(
    const float* __restrict__ a, const void* __restrict__ mask,
    unsigned short* __restrict__ at_sw, int* __restrict__ flag)
{
    int idx = blockIdx.x * 256 + threadIdx.x;   // 0..16383
    int j    = idx & 7;
    int lane = (idx >> 3) & 63;
    int kbnt = idx >> 9;          // 0..31
    int kb   = kbnt & 7;
    int nt   = kbnt >> 3;
    int d  = kb * 32 + (lane >> 4) * 8 + j;
    int kf = nt * 16 + (lane & 15);
    at_sw[idx] = f2bf(a[d * DA_ + kf]);

    if (blockIdx.x == 0) {
        __shared__ int anynz;
        if (threadIdx.x == 0) anynz = 0;
        __syncthreads();
        const unsigned char* mb = (const unsigned char*)mask;
        int base = threadIdx.x * 4;   // scan first 1024 bytes
        int v = mb[base + 1] | mb[base + 2] | mb[base + 3];
        if (v) atomicOr(&anynz, 1);
        __syncthreads();
        if (threadIdx.x == 0) *flag = (anynz == 0) ? 1 : 0;
    }
}

// Kernel 1: e[b,s] = sum_k tanh( dot(h[b,s,:], A[:,k]) ) * bvec[k]
// Also writes h16 = fp16 copy of h (for pass 3).
// One block = 64 sequence rows. MFMA 16x16x32 bf16, N=64 (4 n-tiles), K=256.
__global__ __launch_bounds__(256) void logits_kernel(
    const float* __restrict__ h, const unsigned short* __restrict__ at_sw,
    const float* __restrict__ bvec, float* __restrict__ e,
    unsigned short* __restrict__ h16)
{
    __shared__ unsigned short hs[64 * 264];   // 64 rows, K=256 + 8 pad (bf16)
    const int t = threadIdx.x;
    const long long s0 = (long long)blockIdx.x * 64;
    const float* hblk = h + s0 * DIM_;
    unsigned short* h16blk = h16 + s0 * DIM_;

    // Stage: 64x256 fp32 -> bf16 LDS + fp16 global copy.
    // Each thread-iter handles 8 consecutive floats (two float4s).
    #pragma unroll
    for (int j = 0; j < 8; ++j) {
        int f2 = t + j * 256;            // 8-float chunk index, 0..2047
        int row = f2 >> 5;               // 32 chunks per 256-float row
        int col = (f2 & 31) * 8;
        const float* src = hblk + row * DIM_ + col;
        float4 v0 = *(const float4*)(src);
        float4 v1 = *(const float4*)(src + 4);
        // bf16 -> LDS
        uint2 p0, p1;
        p0.x = f2bf(v0.x) | ((unsigned)f2bf(v0.y) << 16);
        p0.y = f2bf(v0.z) | ((unsigned)f2bf(v0.w) << 16);
        p1.x = f2bf(v1.x) | ((unsigned)f2bf(v1.y) << 16);
        p1.y = f2bf(v1.z) | ((unsigned)f2bf(v1.w) << 16);
        *(uint2*)&hs[row * 264 + col]     = p0;
        *(uint2*)&hs[row * 264 + col + 4] = p1;
        // fp16 -> global (16 B/lane, coalesced)
        union { _Float16 hh[8]; uint4 u; } pk;
        pk.hh[0] = (_Float16)v0.x; pk.hh[1] = (_Float16)v0.y;
        pk.hh[2] = (_Float16)v0.z; pk.hh[3] = (_Float16)v0.w;
        pk.hh[4] = (_Float16)v1.x; pk.hh[5] = (_Float16)v1.y;
        pk.hh[6] = (_Float16)v1.z; pk.hh[7] = (_Float16)v1.w;
        *(uint4*)(h16blk + (size_t)f2 * 8) = pk.u;
    }
    __syncthreads();

    const int wave = t >> 6;
    const int lane = t & 63;
    const int quad = lane >> 4;     // 0..3
    const int nrow = lane & 15;

    float4v acc[4];
    #pragma unroll
    for (int nt = 0; nt < 4; ++nt) acc[nt] = (float4v){0.f, 0.f, 0.f, 0.f};

    const unsigned short* hrow = &hs[(wave * 16 + nrow) * 264];
    #pragma unroll
    for (int kb = 0; kb < 8; ++kb) {
        short8 afrag = *(const short8*)(hrow + kb * 32 + quad * 8);
        #pragma unroll
        for (int nt = 0; nt < 4; ++nt) {
            // coalesced: lane-contiguous 16 B fragments
            short8 bfrag = *(const short8*)(at_sw + ((nt * 8 + kb) * 64 + lane) * 8);
            acc[nt] = __builtin_amdgcn_mfma_f32_16x16x32_bf16(afrag, bfrag, acc[nt], 0, 0, 0);
        }
    }

    // Epilogue: e[row] = sum over 64 cols of tanh(z)*b[col].
    // D layout: col = nrow (per n-tile), row = quad*4 + reg.
    float bv[4];
    #pragma unroll
    for (int nt = 0; nt < 4; ++nt) bv[nt] = bvec[nt * 16 + nrow];

    #pragma unroll
    for (int r = 0; r < 4; ++r) {
        float p = 0.f;
        #pragma unroll
        for (int nt = 0; nt < 4; ++nt) p += tanhf(acc[nt][r]) * bv[nt];
        p += __shfl_xor(p, 1);
        p += __shfl_xor(p, 2);
        p += __shfl_xor(p, 4);
        p += __shfl_xor(p, 8);
        if (nrow == r)
            e[s0 + wave * 16 + quad * 4 + r] = p;
    }
}

// Kernel 2: per-batch masked softmax over S, in place (e -> weights).
__global__ __launch_bounds__(1024) void softmax_kernel(
    float* __restrict__ e, const void* __restrict__ mask, const int* __restrict__ flag)
{
    const int b = blockIdx.x;
    const int t = threadIdx.x;
    const bool int32enc = (*flag != 0);
    const long long base = (long long)b * S_;

    float ev[4];
    #pragma unroll
    for (int i = 0; i < 4; ++i) {
        int s = t + i * 1024;
        float x = e[base + s];
        int m;
        if (int32enc) m = ((const int*)mask)[base + s];
        else          m = ((const unsigned char*)mask)[base + s];
        ev[i] = m ? NEG_ : x;
    }

    __shared__ float red[16];
    float mx = fmaxf(fmaxf(ev[0], ev[1]), fmaxf(ev[2], ev[3]));
    #pragma unroll
    for (int off = 32; off >= 1; off >>= 1) mx = fmaxf(mx, __shfl_xor(mx, off));
    if ((t & 63) == 0) red[t >> 6] = mx;
    __syncthreads();
    float m = red[0];
    #pragma unroll
    for (int i = 1; i < 16; ++i) m = fmaxf(m, red[i]);
    __syncthreads();

    float ex[4];
    float l = 0.f;
    #pragma unroll
    for (int i = 0; i < 4; ++i) { ex[i] = __expf(ev[i] - m); l += ex[i]; }
    #pragma unroll
    for (int off = 32; off >= 1; off >>= 1) l += __shfl_xor(l, off);
    if ((t & 63) == 0) red[t >> 6] = l;
    __syncthreads();
    float lt = 0.f;
    #pragma unroll
    for (int i = 0; i < 16; ++i) lt += red[i];

    float inv = 1.0f / lt;
    #pragma unroll
    for (int i = 0; i < 4; ++i) e[base + t + i * 1024] = ex[i] * inv;
}

// Kernel 3: out[b,d] = sum_s w[b,s] * h16[b,s,d], fp16 h copy.
// Grid = B * 8 blocks; each block covers 512 s-rows.
// Thread layout: wave w = t>>6 handles s ≡ w (mod 4); lane owns 4 consecutive d.
__global__ __launch_bounds__(256) void wsum_kernel(
    const unsigned short* __restrict__ h16, const float* __restrict__ w,
    float* __restrict__ out)
{
    const int b = blockIdx.x >> 3;
    const int c = blockIdx.x & 7;
    const int t = threadIdx.x;
    const int wv = t >> 6;
    const int col = (t & 63) * 4;

    __shared__ float wch[512];
    __shared__ float red[4 * 256];
    const int sbase = c * 512;
    wch[t]       = w[(long long)b * S_ + sbase + t];
    wch[t + 256] = w[(long long)b * S_ + sbase + t + 256];
    __syncthreads();

    const unsigned short* hb = h16 + ((long long)b * S_ + sbase) * DIM_;
    float a0 = 0.f, a1 = 0.f, a2 = 0.f, a3 = 0.f;
    #pragma unroll 4
    for (int i = 0; i < 128; ++i) {
        int s = i * 4 + wv;
        union { ushort4 u; _Float16 hh[4]; } pk;
        pk.u = *(const ushort4*)(hb + (size_t)s * DIM_ + col);
        float wt = wch[s];
        a0 = fmaf(wt, (float)pk.hh[0], a0);
        a1 = fmaf(wt, (float)pk.hh[1], a1);
        a2 = fmaf(wt, (float)pk.hh[2], a2);
        a3 = fmaf(wt, (float)pk.hh[3], a3);
    }
    red[wv * 256 + col + 0] = a0;
    red[wv * 256 + col + 1] = a1;
    red[wv * 256 + col + 2] = a2;
    red[wv * 256 + col + 3] = a3;
    __syncthreads();

    // thread t sums column t across the 4 waves, one atomic per col per block
    float sum = red[t] + red[256 + t] + red[512 + t] + red[768 + t];
    atomicAdd(&out[b * DIM_ + t], sum);
}

extern "C" void kernel_launch(void* const* d_in, const int* in_sizes, int n_in,
                              void* d_out, int out_size, void* d_ws, size_t ws_size,
                              hipStream_t stream) {
    const float* h    = (const float*)d_in[0];
    const void*  mask = d_in[1];
    const float* a    = (const float*)d_in[2];
    const float* bvec = (const float*)d_in[3];
    float* out = (float*)d_out;

    char* ws = (char*)d_ws;
    unsigned short* at_sw = (unsigned short*)ws;           // 32768 B
    int* flag             = (int*)(ws + 32768);
    float* e              = (float*)(ws + 36864);          // 1 MiB
    unsigned short* h16   = (unsigned short*)(ws + 1085440); // 128 MiB fp16 h

    hipMemsetAsync(d_out, 0, (size_t)B_ * DIM_ * sizeof(float), stream);
    prep_kernel<<<64, 256, 0, stream>>>(a, mask, at_sw, flag);
    logits_kernel<<<(B_ * S_) / 64, 256, 0, stream>>>(h, at_sw, bvec, e, h16);
    softmax_kernel<<<B_, 1024, 0, stream>>>(e, mask, flag);
    wsum_kernel<<<B_ * 8, 256, 0, stream>>>(h16, e, out);
}

// Round 3
// 377.293 us; speedup vs baseline: 1.1896x; 1.1155x over previous
//
#include <hip/hip_runtime.h>
#include <hip/hip_bf16.h>

#define B_      64
#define S_      4096
#define DIM_    256
#define DA_     64
#define NEG_    (-1e30f)
#define CHUNKS_ 16
#define ROWS_   256           // seq rows per chunk
#define TILES_  4             // 64-row tiles per chunk
#define LDH_    264           // halves per LDS row (256 + 8 pad)
#define PSTR_   258           // partial stride: m, l, acc[256]

typedef _Float16 half8 __attribute__((ext_vector_type(8)));
typedef float float4v __attribute__((ext_vector_type(4)));

// Kernel 0: A (DIM x DA fp32) -> fp16 swizzled into exact MFMA B-fragment order,
// and detect mask encoding: flag=1 => int32 elements, flag=0 => 1-byte.
// at_sw index: ((nt*8+kb)*64 + lane)*8 + j  = A[d][kf],
//   d = kb*32 + (lane>>4)*8 + j, kf = nt*16 + (lane&15)
__global__ __launch_bounds__(256) void prep_kernel(
    const float* __restrict__ a, const void* __restrict__ mask,
    _Float16* __restrict__ at_sw, int* __restrict__ flag)
{
    int idx = blockIdx.x * 256 + threadIdx.x;   // 0..16383
    int j    = idx & 7;
    int lane = (idx >> 3) & 63;
    int kbnt = idx >> 9;
    int kb   = kbnt & 7;
    int nt   = kbnt >> 3;
    int d  = kb * 32 + (lane >> 4) * 8 + j;
    int kf = nt * 16 + (lane & 15);
    at_sw[idx] = (_Float16)a[d * DA_ + kf];

    if (blockIdx.x == 0) {
        __shared__ int anynz;
        if (threadIdx.x == 0) anynz = 0;
        __syncthreads();
        const unsigned char* mb = (const unsigned char*)mask;
        int base = threadIdx.x * 4;   // scan first 1024 bytes
        int v = mb[base + 1] | mb[base + 2] | mb[base + 3];
        if (v) atomicOr(&anynz, 1);
        __syncthreads();
        if (threadIdx.x == 0) *flag = (anynz == 0) ? 1 : 0;
    }
}

// Kernel 1: fused logits + masked online-softmax + weighted accumulation.
// One block = (batch b, chunk c of 256 seq rows). Single pass over h.
// Writes per-chunk partial: [m, l, acc[256]].
__global__ __launch_bounds__(256) void fused_kernel(
    const float* __restrict__ h, const _Float16* __restrict__ at_sw,
    const float* __restrict__ bvec, const void* __restrict__ mask,
    const int* __restrict__ flag, float* __restrict__ part)
{
    __shared__ _Float16 hf[64 * LDH_];   // 33,792 B
    __shared__ float e_l[64];
    __shared__ float w_l[64];
    __shared__ float red[4 * 256];       // 4 KiB (cross-wave acc reduce)
    __shared__ float m_s, l_s, resc_s;

    const int t = threadIdx.x;
    const int b = blockIdx.x >> 4;
    const int c = blockIdx.x & (CHUNKS_ - 1);
    const int wave = t >> 6;
    const int lane = t & 63;
    const int quad = lane >> 4;
    const int nrow = lane & 15;
    const bool int32enc = (*flag != 0);

    if (t == 0) { m_s = NEG_; l_s = 0.f; }

    const float* hb = h + ((long long)b * S_ + c * ROWS_) * DIM_;
    float bv[4];
    #pragma unroll
    for (int nt = 0; nt < 4; ++nt) bv[nt] = bvec[nt * 16 + nrow];

    const int dbase = (t & 63) * 4;   // 4 consecutive dims owned by this thread
    float acc0 = 0.f, acc1 = 0.f, acc2 = 0.f, acc3 = 0.f;

    for (int tile = 0; tile < TILES_; ++tile) {
        // ---- stage 64 rows fp32 -> fp16 LDS ----
        const float* hsrc = hb + (size_t)tile * 64 * DIM_;
        #pragma unroll
        for (int j = 0; j < 8; ++j) {
            int f2 = t + j * 256;            // 8-float chunk id, 0..2047
            int row = f2 >> 5;
            int col = (f2 & 31) * 8;
            const float* src = hsrc + row * DIM_ + col;
            float4 v0 = *(const float4*)(src);
            float4 v1 = *(const float4*)(src + 4);
            union { _Float16 hh[8]; uint4 u; } pk;
            pk.hh[0] = (_Float16)v0.x; pk.hh[1] = (_Float16)v0.y;
            pk.hh[2] = (_Float16)v0.z; pk.hh[3] = (_Float16)v0.w;
            pk.hh[4] = (_Float16)v1.x; pk.hh[5] = (_Float16)v1.y;
            pk.hh[6] = (_Float16)v1.z; pk.hh[7] = (_Float16)v1.w;
            *(uint4*)&hf[row * LDH_ + col] = pk.u;
        }
        __syncthreads();

        // ---- MFMA f16: e for 64 rows (wave w owns rows w*16..w*16+15) ----
        float4v accm[4];
        #pragma unroll
        for (int nt = 0; nt < 4; ++nt) accm[nt] = (float4v){0.f, 0.f, 0.f, 0.f};
        const _Float16* hrow = &hf[(wave * 16 + nrow) * LDH_];
        #pragma unroll
        for (int kb = 0; kb < 8; ++kb) {
            half8 af = *(const half8*)(hrow + kb * 32 + quad * 8);
            #pragma unroll
            for (int nt = 0; nt < 4; ++nt) {
                half8 bf = *(const half8*)(at_sw + ((nt * 8 + kb) * 64 + lane) * 8);
                accm[nt] = __builtin_amdgcn_mfma_f32_16x16x32_f16(af, bf, accm[nt], 0, 0, 0);
            }
        }
        // epilogue: e[m] = sum_n tanh(z[m][n]) * b[n];  D: col=nrow, row=quad*4+r
        #pragma unroll
        for (int r = 0; r < 4; ++r) {
            float p = 0.f;
            #pragma unroll
            for (int nt = 0; nt < 4; ++nt) p += tanhf(accm[nt][r]) * bv[nt];
            p += __shfl_xor(p, 1);
            p += __shfl_xor(p, 2);
            p += __shfl_xor(p, 4);
            p += __shfl_xor(p, 8);
            if (nrow == r) e_l[wave * 16 + quad * 4 + r] = p;
        }
        __syncthreads();

        // ---- wave 0: mask + online-softmax state update ----
        if (wave == 0) {
            long long mi = (long long)b * S_ + c * ROWS_ + tile * 64 + lane;
            int mv = int32enc ? ((const int*)mask)[mi]
                              : (int)((const unsigned char*)mask)[mi];
            float ev = mv ? NEG_ : e_l[lane];
            float mx = ev;
            #pragma unroll
            for (int off = 32; off >= 1; off >>= 1) mx = fmaxf(mx, __shfl_xor(mx, off));
            float m_old = m_s;
            float m_new = fmaxf(m_old, mx);
            float wv_ = __expf(ev - m_new);
            w_l[lane] = wv_;
            float sm = wv_;
            #pragma unroll
            for (int off = 32; off >= 1; off >>= 1) sm += __shfl_xor(sm, off);
            if (lane == 0) {
                float rs = __expf(m_old - m_new);
                l_s = l_s * rs + sm;
                m_s = m_new;
                resc_s = rs;
            }
        }
        __syncthreads();

        // ---- all waves: rescale + accumulate own s-subset (s ≡ wave mod 4) ----
        float rs = resc_s;
        acc0 *= rs; acc1 *= rs; acc2 *= rs; acc3 *= rs;
        #pragma unroll 4
        for (int i = 0; i < 16; ++i) {
            int s = i * 4 + wave;
            float ws = w_l[s];
            union { ushort4 u; _Float16 hh[4]; } pk;
            pk.u = *(const ushort4*)((const unsigned short*)&hf[s * LDH_ + dbase]);
            acc0 = fmaf(ws, (float)pk.hh[0], acc0);
            acc1 = fmaf(ws, (float)pk.hh[1], acc1);
            acc2 = fmaf(ws, (float)pk.hh[2], acc2);
            acc3 = fmaf(ws, (float)pk.hh[3], acc3);
        }
        __syncthreads();   // protects hf/w_l/state before next tile
    }

    // ---- cross-wave reduce + write partial ----
    red[wave * 256 + dbase + 0] = acc0;
    red[wave * 256 + dbase + 1] = acc1;
    red[wave * 256 + dbase + 2] = acc2;
    red[wave * 256 + dbase + 3] = acc3;
    __syncthreads();
    float sum = red[t] + red[256 + t] + red[512 + t] + red[768 + t];
    float* pc = part + (size_t)(b * CHUNKS_ + c) * PSTR_;
    pc[2 + t] = sum;
    if (t == 0) { pc[0] = m_s; pc[1] = l_s; }
}

// Kernel 2: merge per-chunk partials -> out[b][d]
__global__ __launch_bounds__(256) void merge_kernel(
    const float* __restrict__ part, float* __restrict__ out)
{
    const int b = blockIdx.x;
    const int t = threadIdx.x;
    const float* pb = part + (size_t)b * CHUNKS_ * PSTR_;
    float M = NEG_;
    #pragma unroll
    for (int c = 0; c < CHUNKS_; ++c) M = fmaxf(M, pb[c * PSTR_]);
    float L = 0.f, o = 0.f;
    #pragma unroll
    for (int c = 0; c < CHUNKS_; ++c) {
        float sc = __expf(pb[c * PSTR_] - M);
        L += pb[c * PSTR_ + 1] * sc;
        o += pb[c * PSTR_ + 2 + t] * sc;
    }
    out[b * DIM_ + t] = o / L;
}

extern "C" void kernel_launch(void* const* d_in, const int* in_sizes, int n_in,
                              void* d_out, int out_size, void* d_ws, size_t ws_size,
                              hipStream_t stream) {
    const float* h    = (const float*)d_in[0];
    const void*  mask = d_in[1];
    const float* a    = (const float*)d_in[2];
    const float* bvec = (const float*)d_in[3];
    float* out = (float*)d_out;

    char* ws = (char*)d_ws;
    _Float16* at_sw = (_Float16*)ws;              // 32,768 B
    int* flag       = (int*)(ws + 32768);
    float* part     = (float*)(ws + 36864);       // 64*16*258*4 ≈ 1 MiB

    prep_kernel<<<64, 256, 0, stream>>>(a, mask, at_sw, flag);
    fused_kernel<<<B_ * CHUNKS_, 256, 0, stream>>>(h, at_sw, bvec, mask, flag, part);
    merge_kernel<<<B_, 256, 0, stream>>>(part, out);
}